// Round 9
// baseline (141.209 us; speedup 1.0000x reference)
//
#include <hip/hip_runtime.h>
#include <math.h>

// Problem: B=8, V=8, N=1000, D=256, H=8, KS=32
// 3 launches. Rules learned r3-r10: sync ONLY at kernel boundaries (~4us each;
// intra-kernel cross-XCD sync = 60-100us); keep phases wide (r7); no redundant
// strided Mw recompute (r6); no serial global probes (r8); probe ONCE in
// k_prep (r10).
// r11: LDS-stage multiply-reused operands: 157 -> 146us.
// r12: gKs staged (pad-36), hstat register-blocked, s8 overlapped: -> 143us.
// r13: fold k_fq into k_logits (4 -> 3 kernels): -> 139us.
// r14 REGRESSED (143.6): price BOTH sides of a layout change.
// r15: lqm overlapped with main dot: -> 138.4us (best). k_logits largest.
// r16: epilogue parallel atomic loads: k_logits <43.6, dur flat (138.5).
// r17 REGRESSED (146.5): more waves don't help pipe-bound phases.
// r18 NEUTRAL (138.5): coalesced hac/s8F slot gathers — they were hidden
//      under the bkL staging window, not on the critical path.
// r19 (this round): fq's po row-gather = 64 lines per wave-instr through the
//      TCP (16K line-lookups/CU ~ 6-7us). k_prep (+64 blocks) transposes po
//      -> poT[e][col] in ws (reads gather off-critical-path, writes
//      coalesced); fq reads poT as 4 coalesced b32 per e (4 lines/instr,
//      4x fewer lookups). Same values, same expression, same e-chain ->
//      bit-exact.
//
// ws float offsets — partial-slot handoff, NO zero-init required.
#define OFF_MW     0          // 768*8 = 6144 (rows 0..255 V, 256..511 K, 512..767 L)
#define OFF_QUERY  6144       // 64*256 -> 22528
#define OFF_CSUMP  22528      // [512]      -> 23040
#define OFF_HSTATP 23040      // [512*256]  -> 154112
#define OFF_S8P    154112     // [512*64]   -> 186880
#define OFF_EXPSP  203776     // [256]      -> 204032
#define OFF_PACKP  204032     // [256 u64]  -> 204544 (byte-offset %8 == 0)
#define OFF_DONE   204544     // [1] zeroed by k_prep
#define OFF_BM     204545     // [1] mask dtype flag, written by k_prep
#define OFF_POT    204548     // [256*256] poT[e][col] -> 270084

__device__ inline float waveSum(float v){
  #pragma unroll
  for (int o = 32; o > 0; o >>= 1) v += __shfl_down(v, o, 64);
  return v;
}
__device__ inline unsigned long long waveMaxU(unsigned long long v){
  #pragma unroll
  for (int o = 32; o > 0; o >>= 1) {
    unsigned long long w = __shfl_down(v, o, 64);
    v = (w > v) ? w : v;
  }
  return v;
}
__device__ inline unsigned encF(float f){
  unsigned u = __float_as_uint(f);
  return (u & 0x80000000u) ? ~u : (u | 0x80000000u);
}
__device__ inline float decF(unsigned u){
  return (u & 0x80000000u) ? __uint_as_float(u & 0x7fffffffu)
                           : __uint_as_float(~u);
}

// ---------------- K_prep: 897 blocks ----------------
// [0,768): Mw row per block (coalesced); [768,832): query per (b,v);
// 832: parallel mask-dtype probe + DONE zero; [833,897): poT transpose.
__global__ __launch_bounds__(256) void k_prep(
    const float* __restrict__ pns1, const float* __restrict__ pns2,
    const float* __restrict__ prev, const float* __restrict__ veh,
    const float* __restrict__ fixedc, const float* __restrict__ pcs,
    const void* __restrict__ maskp, const float* __restrict__ po,
    float* __restrict__ W)
{
  int blk = blockIdx.x, tid = threadIdx.x;
  float* mw     = W + OFF_MW;
  float* queryp = W + OFF_QUERY;

  if (blk < 768) {
    // Mw[i][f<7] = pns1[i,f] + sum_j pns2[i,j]*pns1[j,f]; Mw[i][7]=pns2[i,768]
    int i = blk;
    __shared__ float red[28];
    const float* row = pns2 + (size_t)i * 769;
    float acc[7] = {0.f,0.f,0.f,0.f,0.f,0.f,0.f};
    #pragma unroll
    for (int t = 0; t < 3; t++) {
      int j = tid + 256 * t;              // lane-contiguous: coalesced
      float r = row[j];
      const float* w = pns1 + j * 7;
      #pragma unroll
      for (int f = 0; f < 7; f++) acc[f] += r * w[f];
    }
    #pragma unroll
    for (int f = 0; f < 7; f++) {
      float v = waveSum(acc[f]);
      if ((tid & 63) == 0) red[(tid >> 6) * 7 + f] = v;
    }
    __syncthreads();
    if (tid < 7) {
      float s = red[tid] + red[7 + tid] + red[14 + tid] + red[21 + tid];
      mw[i * 8 + tid] = pns1[i * 7 + tid] + s;
    } else if (tid == 7) {
      mw[i * 8 + 7] = row[768];
    }
  } else if (blk < 832) {
    int bv = blk - 768;
    __shared__ __align__(16) float cvs[264];
    cvs[tid] = prev[(size_t)bv * 256 + tid];
    if (tid < 8) cvs[256 + tid] = veh[bv * 8 + tid];
    __syncthreads();
    int b = bv >> 3;
    float a = fixedc[b * 256 + tid];
    const float4* c4 = (const float4*)cvs;
    const float4* w4 = (const float4*)(pcs + (size_t)tid * 264);
    #pragma unroll 8
    for (int k = 0; k < 66; k++) {
      float4 cv = c4[k], wv = w4[k];
      a += cv.x*wv.x + cv.y*wv.y + cv.z*wv.z + cv.w*wv.w;
    }
    queryp[(size_t)bv * 256 + tid] = a;
  } else if (blk == 832) {
    // parallel mask-dtype probe: int32 bool has bytes idx%4!=0 all zero;
    // u8 bool has ~70% of them nonzero. One byte per thread + ballot.
    __shared__ unsigned hits[4];
    const unsigned char* mb = (const unsigned char*)maskp;
    bool hit = (tid > 0) && ((tid & 3) != 0) && (mb[tid] != 0);
    unsigned long long bal = __ballot(hit);
    if ((tid & 63) == 0) hits[tid >> 6] = (bal != 0ull) ? 1u : 0u;
    __syncthreads();
    if (tid == 0) {
      ((unsigned*)(W + OFF_BM))[0] = hits[0] | hits[1] | hits[2] | hits[3];
      ((unsigned*)(W + OFF_DONE))[0] = 0u;
    }
  } else {
    // r19: poT transpose. Block bb handles poT rows r = bb*4..+3.
    // Read po[tid][r] (gather, off critical path); write poT[r][tid] coalesced.
    int bb = blk - 833;
    float* poT = W + OFF_POT;
    #pragma unroll
    for (int j = 0; j < 4; j++) {
      int r = bb * 4 + j;
      poT[(size_t)r * 256 + tid] = po[(size_t)tid * 256 + r];
    }
  }
}

// ---------------- K_attn: 512 blocks = (h, c, b) ----------------
// compat -> exp (no max-sub; shift-invariant) -> partial slots (plain stores).
// r12: gKs slice staged (pad-36 rows); hstat register-blocked on wave 0
// (float4 acc, b128 gvL reads, v-broadcast conflict-free); s8 on tids 64..255
// overlapping hstat. LDS = 73.3 KB -> 2 blocks/CU.
__global__ __launch_bounds__(256) void k_attn(
    const float* __restrict__ node_dyn, const float* __restrict__ gVs,
    const float* __restrict__ gKs, const void* __restrict__ maskp,
    float* __restrict__ W)
{
  const int blk = blockIdx.x, tid = threadIdx.x;
  const int b = blk & 7, c = (blk >> 3) & 7, h = blk >> 6;
  const int n0 = c * 125;
  const float* mw     = W + OFF_MW;
  const float* queryp = W + OFF_QUERY;
  float* csum_p  = W + OFF_CSUMP;
  float* hstat_p = W + OFF_HSTATP;
  float* s8_p    = W + OFF_S8P;
  const int bytemode = *(const int*)(W + OFF_BM);   // uniform scalar load

  __shared__ __align__(16) float p[1000];
  __shared__ __align__(16) float gq[256];
  __shared__ float mwK[256];                 // [k=32][f=8], contiguous mw block
  __shared__ float qmk[64];
  __shared__ float red4[4];
  __shared__ float s8part[256];
  __shared__ __align__(16) float gvL[4000];  // [i=125][k=32] gVs slice
  __shared__ __align__(16) float gkL[4500];  // [i=125][36-pad] gKs slice
  __shared__ __align__(16) float ndL[8000];  // [e=1000][f=8] node_dyn slice

  gq[tid]  = queryp[(size_t)(b * 8 + (tid >> 5)) * 256 + h * 32 + (tid & 31)];
  mwK[tid] = mw[(256 + h * 32) * 8 + tid];   // coalesced 1 KB block
  __syncthreads();
  if (tid < 64) {
    int v = tid >> 3, f = tid & 7;
    float a = 0.f;
    #pragma unroll
    for (int k = 0; k < 32; k++)
      a += gq[v * 32 + k] * mwK[k * 8 + f];
    qmk[tid] = a;
  }
  // stage gVs + gKs slices while qmk computes: 2x 1000 float4, coalesced
  {
    const float4* gv4 = (const float4*)(gVs + ((size_t)(h * 8 + b) * 1000 + n0) * 32);
    const float4* gk4 = (const float4*)(gKs + ((size_t)(h * 8 + b) * 1000 + n0) * 32);
    for (int idx = tid; idx < 1000; idx += 256) {
      int row = idx >> 3, c4 = idx & 7;
      ((float4*)gvL)[idx] = gv4[idx];
      ((float4*)(gkL + row * 36))[c4] = gk4[idx];
    }
  }
  __syncthreads();

  float tsum = 0.f;
  for (int e = tid; e < 1000; e += 256) {
    int v = e / 125;
    int i = e - v * 125;
    int n = n0 + i;
    int bvn = (b * 8 + v) * 1000 + n;
    const float4* nd4 = (const float4*)(node_dyn + (size_t)bvn * 8);
    float4 ndA = nd4[0], ndB = nd4[1];
    ((float4*)ndL)[e * 2]     = ndA;          // capture for s8 phase
    ((float4*)ndL)[e * 2 + 1] = ndB;
    const float4* gk4 = (const float4*)(gkL + i * 36);
    const float4* gq4 = (const float4*)(gq + v * 32);
    float s = 0.f;
    #pragma unroll
    for (int k4 = 0; k4 < 8; k4++) {
      float4 g = gk4[k4], q = gq4[k4];
      s += g.x*q.x + g.y*q.y + g.z*q.z + g.w*q.w;
    }
    const float* qm = qmk + v * 8;
    float dyn = ndA.x*qm[0] + ndA.y*qm[1] + ndA.z*qm[2] + ndA.w*qm[3]
              + ndB.x*qm[4] + ndB.y*qm[5] + ndB.z*qm[6] + ndB.w*qm[7];
    bool on = bytemode ? (((const unsigned char*)maskp)[bvn] != 0)
                       : (((const int*)maskp)[bvn] != 0);
    float cc = (s + dyn) * 0.17677669529663687f + (on ? 0.f : -INFINITY);
    float pv = __expf(cc);
    p[e] = pv;
    tsum += pv;
  }
  tsum = waveSum(tsum);
  if ((tid & 63) == 0) red4[tid >> 6] = tsum;
  __syncthreads();
  if (tid == 0) csum_p[blk] = red4[0] + red4[1] + red4[2] + red4[3];

  if (tid < 64) {
    // hstat partial [v][k] — register-blocked: 4 outputs/thread (kq quad).
    // gvL b128: 8 distinct 4-bank groups, v-lanes broadcast -> conflict-free.
    // Each output's i-chain identical to r11 -> bit-exact.
    int v = tid >> 3, kq = tid & 7;
    const float* pr = p + v * 125;
    const float4* gv4 = ((const float4*)gvL) + kq;
    float4 a = make_float4(0.f, 0.f, 0.f, 0.f);
    #pragma unroll 5
    for (int i = 0; i < 125; i++) {
      float pi = pr[i];
      float4 g = gv4[i * 8];
      a.x += pi * g.x; a.y += pi * g.y; a.z += pi * g.z; a.w += pi * g.w;
    }
    ((float4*)(hstat_p + (size_t)blk * 256))[tid] = a;
  } else {
    // s8 partial [v][f], 4-way i-split — same slots/chains as r11, now on
    // threads 64..255 so it overlaps hstat. Threads 64..127 take 2 slots.
    int j0 = tid - 64;                       // 0..191
    #pragma unroll
    for (int rep = 0; rep < 2; rep++) {
      int t = j0 + rep * 192;
      if (t < 256) {
        int sidx = t & 3, vf = t >> 2;
        int v = vf >> 3, f = vf & 7;
        int i0 = sidx * 32;
        int iN = (sidx == 3) ? 29 : 32;      // 32+32+32+29 = 125
        const float* nd = ndL + ((size_t)(v * 125 + i0)) * 8 + f;
        const float* pr = p + v * 125 + i0;
        float a = 0.f;
        for (int i = 0; i < iN; i++) a += pr[i] * nd[i * 8];
        s8part[sidx * 64 + vf] = a;
      }
    }
  }
  __syncthreads();
  if (tid < 64)
    s8_p[(size_t)blk * 64 + tid] = s8part[tid] + s8part[64 + tid]
                                 + s8part[128 + tid] + s8part[192 + tid];
}

// ---------------- K_logits: 256 blocks = (b, slice of 32 nodes) -------------
// r13 fused: each block recomputes its b's fq[8][256] + lqm[8][8] from the
// k_attn partial slots with EXACTLY k_fq's accumulation chains (bit-exact),
// then does the per-(v,n) logit dot from LDS. Ticket last block -> outputs.
// r15: lqm (wave 0) overlapped with the main dot; barrier before lqmF use.
// r16: ticket-255 epilogue: parallel relaxed device-scope atomic loads.
// r18: hac + s8F slot-reduces as coalesced f4 accumulation (hacL overlays
// fqlL, disjoint lifetimes).
// r19: fq reads poT (4 coalesced b32 per e, 4 lines/instr vs 64) — same
// values, same expression, same e-chain.
__global__ __launch_bounds__(256) void k_logits(
    const float* __restrict__ lKs, const float* __restrict__ node_dyn,
    const void* __restrict__ maskp, float* __restrict__ W,
    float* __restrict__ out)
{
  const int blk = blockIdx.x, tid = threadIdx.x;
  const int b = blk & 7, slice = blk >> 3;
  const int nn = tid >> 3, v = tid & 7;
  const int n = slice * 32 + nn;
  const bool valid = (n < 1000);
  const int n_c = valid ? n : 999;
  const float* mwgV    = W + OFF_MW;            // rows 0..255
  const float* mwgL    = W + OFF_MW + 512 * 8;  // rows 512..767
  const float* csum_p  = W + OFF_CSUMP;
  const float* hstat_p = W + OFF_HSTATP;
  const float* s8_p    = W + OFF_S8P;
  const float* poT     = W + OFF_POT;
  float* expsum_p = W + OFF_EXPSP;
  unsigned long long* packed_p = (unsigned long long*)(W + OFF_PACKP);
  unsigned* done = (unsigned*)(W + OFF_DONE);
  const int bytemode = *(const int*)(W + OFF_BM);   // uniform scalar load

  __shared__ __align__(16) float bkL[32 * 260];     // 32 lKs rows, +4f pad
  __shared__ __align__(16) float clL[8 * 256];      // conc rows (broadcast-read)
  __shared__ __align__(16) float fqlL[8 * 260];     // fq rows / hacL overlay
  __shared__ float s8F[512];
  __shared__ float csumF[8];
  __shared__ float mwLL[2048];                      // mwgL staged coalesced
  __shared__ float lqmF[64];
  __shared__ float red4[4];
  __shared__ unsigned long long rP[4];
  __shared__ unsigned ticket;
  __shared__ float sS[256];                         // r16: parallel slot stage
  __shared__ unsigned long long sP[256];

  // (1) stage 32 lKs rows (clamped like n_c), coalesced: 2048 float4 total
  {
    const float4* src = (const float4*)(lKs + (size_t)b * 1000 * 256);
    for (int idx = tid; idx < 2048; idx += 256) {
      int row = idx >> 6, d4 = idx & 63;
      int ng = slice * 32 + row; if (ng > 999) ng = 999;
      ((float4*)(bkL + row * 260))[d4] = src[(size_t)ng * 64 + d4];
    }
  }
  // (2) s8F slot-reduce: coalesced f4, cc-ascending per element (chain
  // identical to k_fq). tid<128: (h2 = tid>>4, q = f4 pos in 64-float slot).
  if (tid < 128) {
    int h2 = tid >> 4, q = tid & 15;
    float4 a = make_float4(0.f, 0.f, 0.f, 0.f);
    #pragma unroll
    for (int cc = 0; cc < 8; cc++) {
      const float4* sp = (const float4*)(s8_p
          + (size_t)((h2 << 6) | (cc << 3) | b) * 64);
      float4 x = sp[q];
      a.x += x.x; a.y += x.y; a.z += x.z; a.w += x.w;
    }
    ((float4*)s8F)[tid] = a;     // s8F[h2*64 + q*4 ..+3]
  }
  if (tid < 8) {
    float s = 0.f;
    #pragma unroll
    for (int cc = 0; cc < 8; cc++) s += csum_p[(tid << 6) | (cc << 3) | b];
    csumF[tid] = s;
  }
  for (int idx = tid; idx < 2048; idx += 256) mwLL[idx] = mwgL[idx];
  // (3) hac slot-reduce: coalesced f4 pairs, cc-ascending per element
  // (chain identical to k_fq's hac). Staged into hacL = fqlL overlay.
  {
    float* hacL = fqlL;                      // overlay, dies at next barrier+1
    int posq = (tid & 31) * 2;               // two f4 positions in 256-f slot
    float4 a0 = make_float4(0.f, 0.f, 0.f, 0.f);
    float4 a1 = make_float4(0.f, 0.f, 0.f, 0.f);
    #pragma unroll
    for (int cc = 0; cc < 8; cc++) {
      const float4* hp = (const float4*)(hstat_p
          + (size_t)((tid >> 5 << 6) | (cc << 3) | b) * 256);
      float4 x0 = hp[posq], x1 = hp[posq + 1];
      a0.x += x0.x; a0.y += x0.y; a0.z += x0.z; a0.w += x0.w;
      a1.x += x1.x; a1.y += x1.y; a1.z += x1.z; a1.w += x1.w;
    }
    ((float4*)hacL)[tid * 2]     = a0;       // hacL[h2*256 + posq*4 ..]
    ((float4*)hacL)[tid * 2 + 1] = a1;
  }
  __syncthreads();
  // (4) cl rows: same expression as k_fq's cl phase, per v; hac read from
  // hacL (lanes k2 -> distinct banks; 2-way wave aliasing = free).
  {
    const int h2 = tid >> 5, k2 = tid & 31;
    const float* hacL = fqlL;
    float mwr[8];
    const float* mwp = mwgV + tid * 8;
    #pragma unroll
    for (int f = 0; f < 8; f++) mwr[f] = mwp[f];
    float inv = csumF[h2];
    #pragma unroll
    for (int v2 = 0; v2 < 8; v2++) {
      float dyn = 0.f;
      const float* s8pp = s8F + h2 * 64 + v2 * 8;
      #pragma unroll
      for (int f = 0; f < 8; f++) dyn += s8pp[f] * mwr[f];
      clL[v2 * 256 + tid] = (hacL[h2 * 256 + v2 * 32 + k2] + dyn) / inv;
    }
  }
  __syncthreads();
  // (5) fq rows: thread tid computes fq[v][tid] = dot(cl[v], po[tid]) for all
  // v; d4 ascending, same per-iter expression as k_fq -> bit-exact. r19: wv
  // components from poT, 4 coalesced b32 per e (same values). Overwrites hacL.
  {
    float acc[8];
    #pragma unroll
    for (int v2 = 0; v2 < 8; v2++) acc[v2] = 0.f;
    #pragma unroll 4
    for (int e = 0; e < 64; e++) {
      float4 wv;
      wv.x = poT[(size_t)(e * 4 + 0) * 256 + tid];
      wv.y = poT[(size_t)(e * 4 + 1) * 256 + tid];
      wv.z = poT[(size_t)(e * 4 + 2) * 256 + tid];
      wv.w = poT[(size_t)(e * 4 + 3) * 256 + tid];
      #pragma unroll
      for (int v2 = 0; v2 < 8; v2++) {
        float4 cv = ((const float4*)(clL + v2 * 256))[e];
        acc[v2] += cv.x*wv.x + cv.y*wv.y + cv.z*wv.z + cv.w*wv.w;
      }
    }
    #pragma unroll
    for (int v2 = 0; v2 < 8; v2++) fqlL[v2 * 260 + tid] = acc[v2];
  }
  __syncthreads();
  // (6) lqm on wave 0 (k_fq's exact two-level chain) OVERLAPPED with the
  // main-dot s on waves 1-3; barrier moved to before lqmF consumption.
  if (tid < 64) {
    int v2 = tid >> 3, f = tid & 7;
    const float* fr = fqlL + v2 * 260;
    float s2 = 0.f;
    for (int cc2 = 0; cc2 < 32; cc2++) {
      float p2 = 0.f;
      for (int d = cc2 * 8; d < cc2 * 8 + 8; d++) p2 += fr[d] * mwLL[d * 8 + f];
      s2 += p2;
    }
    lqmF[tid] = s2;
  }
  // (7) main logit dot — A from fqlL (260-pad rows: v*260 -> bank quads
  // 4v%32, conflict-free with 8-way broadcast), Bk from bkL as r11.
  int bvn = (b * 8 + v) * 1000 + n_c;
  const float4* A  = (const float4*)(fqlL + v * 260);
  const float4* Bk = (const float4*)(bkL + nn * 260);
  float s = 0.f;
  #pragma unroll 8
  for (int d4 = 0; d4 < 64; d4++) {
    float4 x = A[d4], y = Bk[d4];
    s += x.x*y.x + x.y*y.y + x.z*y.z + x.w*y.w;
  }
  const float4* nd4 = (const float4*)(node_dyn + (size_t)bvn * 8);
  float4 na = nd4[0], nb = nd4[1];
  __syncthreads();                          // lqmF ready
  const float* qm = lqmF + v * 8;
  float dyn = na.x*qm[0] + na.y*qm[1] + na.z*qm[2] + na.w*qm[3]
            + nb.x*qm[4] + nb.y*qm[5] + nb.z*qm[6] + nb.w*qm[7];
  float z = (s + dyn) * 0.0625f;
  bool on = bytemode ? (((const unsigned char*)maskp)[bvn] != 0)
                     : (((const int*)maskp)[bvn] != 0);
  float L = tanhf(z) * 10.0f + (on ? 0.f : -INFINITY);
  if (!valid) L = -INFINITY;
  float ex = __expf(L);                     // exp(-inf)=0
  unsigned idx = (unsigned)(v * 1000 + n_c);
  unsigned long long pk = ((unsigned long long)encF(L) << 32) | (unsigned)(~idx);
  float sEx = waveSum(ex);
  unsigned long long mP = waveMaxU(pk);
  if ((tid & 63) == 0) { red4[tid >> 6] = sEx; rP[tid >> 6] = mP; }
  __syncthreads();
  if (tid == 0) {
    float S = red4[0] + red4[1] + red4[2] + red4[3];
    unsigned long long P = rP[0];
    #pragma unroll
    for (int i = 1; i < 4; i++) P = (rP[i] > P) ? rP[i] : P;
    atomicExch(&expsum_p[blk], S);          // coherent-point slot stores
    atomicExch(&packed_p[blk], P);
    __threadfence();
    ticket = atomicAdd(done, 1u);
  }
  __syncthreads();
  if (ticket == 255) {                      // last block: all slots written
    __threadfence();
    // r16: 256 PARALLEL device-scope relaxed atomic loads into LDS.
    sS[tid] = __hip_atomic_load(&expsum_p[tid], __ATOMIC_RELAXED,
                                __HIP_MEMORY_SCOPE_AGENT);
    sP[tid] = __hip_atomic_load(&packed_p[tid], __ATOMIC_RELAXED,
                                __HIP_MEMORY_SCOPE_AGENT);
    __syncthreads();
    if (tid < 64) {
      float cEnt = 0.f;
      if (tid < 8) {
        float S = 0.f;
        unsigned long long P = 0ull;
        for (int sl = 0; sl < 32; sl++) {
          int j = sl * 8 + tid;             // slots of batch tid — same chain
          S += sS[j];
          unsigned long long q = sP[j];
          P = (q > P) ? q : P;
        }
        float best = decF((unsigned)(P >> 32));
        unsigned bi = ~(unsigned)(P & 0xffffffffu);
        float logprob = best - logf(S);
        float prob = __expf(logprob);
        out[tid]      = (float)(bi / 1000);
        out[8 + tid]  = (float)(bi % 1000);
        out[16 + tid] = logprob;
        cEnt = prob * logprob;
      }
      cEnt = waveSum(cEnt);
      if (tid == 0) out[24] = -cEnt;
    }
  }
}

extern "C" void kernel_launch(void* const* d_in, const int* in_sizes, int n_in,
                              void* d_out, int out_size, void* d_ws, size_t ws_size,
                              hipStream_t stream) {
  const float* fixedc   = (const float*)d_in[1];
  const float* prev     = (const float*)d_in[2];
  const float* node_dyn = (const float*)d_in[3];
  const float* veh      = (const float*)d_in[4];
  const float* gVs      = (const float*)d_in[5];
  const float* gKs      = (const float*)d_in[6];
  const float* lKs      = (const float*)d_in[7];
  const void*  mask     = d_in[8];
  const float* pcs      = (const float*)d_in[9];
  const float* pns1     = (const float*)d_in[10];
  const float* pns2     = (const float*)d_in[11];
  const float* po       = (const float*)d_in[12];
  float* W   = (float*)d_ws;
  float* out = (float*)d_out;

  k_prep<<<897, 256, 0, stream>>>(pns1, pns2, prev, veh, fixedc, pcs, mask, po, W);
  k_attn<<<512, 256, 0, stream>>>(node_dyn, gVs, gKs, mask, W);
  k_logits<<<256, 256, 0, stream>>>(lKs, node_dyn, mask, W, out);
}

// Round 10
// 137.697 us; speedup vs baseline: 1.0255x; 1.0255x over previous
//
#include <hip/hip_runtime.h>
#include <math.h>

// Problem: B=8, V=8, N=1000, D=256, H=8, KS=32
// 3 launches. FINAL (r20): revert to best-measured configuration (r16,
// 138.4-138.5us). History:
// r11: LDS-stage multiply-reused operands: 157 -> 146us.
// r12: gKs staged (pad-36), hstat register-blocked, s8 overlapped: -> 143us.
// r13: fold k_fq into k_logits (4 -> 3 kernels): -> 139us.
// r14 REGRESSED (143.6): price BOTH sides of a layout change.
// r15: lqm overlapped with main dot: -> 138.4us (best).
// r16: epilogue parallel atomic loads: 138.5 (k_logits left top-5).
// r17 REGRESSED (146.5): more waves don't help pipe-bound phases.
// r18 NEUTRAL (138.5): slot gathers were hidden under bkL staging.
// r19 REGRESSED (141.2): poT indirection; fq gather also not critical.
// Conclusion: k_logits' phases mutually hide; its ~43us is a 4-wave
// barrier-chain latency floor. Timed region carries ~86us of harness
// workspace re-poison fill + ~12us boundaries -> structural roofline.
//
// ws float offsets — partial-slot handoff, NO zero-init required.
#define OFF_MW     0          // 768*8 = 6144 (rows 0..255 V, 256..511 K, 512..767 L)
#define OFF_QUERY  6144       // 64*256 -> 22528
#define OFF_CSUMP  22528      // [512]      -> 23040
#define OFF_HSTATP 23040      // [512*256]  -> 154112
#define OFF_S8P    154112     // [512*64]   -> 186880
#define OFF_EXPSP  203776     // [256]      -> 204032
#define OFF_PACKP  204032     // [256 u64]  -> 204544 (byte-offset %8 == 0)
#define OFF_DONE   204544     // [1] zeroed by k_prep
#define OFF_BM     204545     // [1] mask dtype flag, written by k_prep

__device__ inline float waveSum(float v){
  #pragma unroll
  for (int o = 32; o > 0; o >>= 1) v += __shfl_down(v, o, 64);
  return v;
}
__device__ inline unsigned long long waveMaxU(unsigned long long v){
  #pragma unroll
  for (int o = 32; o > 0; o >>= 1) {
    unsigned long long w = __shfl_down(v, o, 64);
    v = (w > v) ? w : v;
  }
  return v;
}
__device__ inline unsigned encF(float f){
  unsigned u = __float_as_uint(f);
  return (u & 0x80000000u) ? ~u : (u | 0x80000000u);
}
__device__ inline float decF(unsigned u){
  return (u & 0x80000000u) ? __uint_as_float(u & 0x7fffffffu)
                           : __uint_as_float(~u);
}

// ---------------- K_prep: 833 blocks ----------------
// [0,768): Mw row per block (coalesced); [768,832): query per (b,v);
// 832: parallel mask-dtype probe + DONE zero.
__global__ __launch_bounds__(256) void k_prep(
    const float* __restrict__ pns1, const float* __restrict__ pns2,
    const float* __restrict__ prev, const float* __restrict__ veh,
    const float* __restrict__ fixedc, const float* __restrict__ pcs,
    const void* __restrict__ maskp, float* __restrict__ W)
{
  int blk = blockIdx.x, tid = threadIdx.x;
  float* mw     = W + OFF_MW;
  float* queryp = W + OFF_QUERY;

  if (blk < 768) {
    // Mw[i][f<7] = pns1[i,f] + sum_j pns2[i,j]*pns1[j,f]; Mw[i][7]=pns2[i,768]
    int i = blk;
    __shared__ float red[28];
    const float* row = pns2 + (size_t)i * 769;
    float acc[7] = {0.f,0.f,0.f,0.f,0.f,0.f,0.f};
    #pragma unroll
    for (int t = 0; t < 3; t++) {
      int j = tid + 256 * t;              // lane-contiguous: coalesced
      float r = row[j];
      const float* w = pns1 + j * 7;
      #pragma unroll
      for (int f = 0; f < 7; f++) acc[f] += r * w[f];
    }
    #pragma unroll
    for (int f = 0; f < 7; f++) {
      float v = waveSum(acc[f]);
      if ((tid & 63) == 0) red[(tid >> 6) * 7 + f] = v;
    }
    __syncthreads();
    if (tid < 7) {
      float s = red[tid] + red[7 + tid] + red[14 + tid] + red[21 + tid];
      mw[i * 8 + tid] = pns1[i * 7 + tid] + s;
    } else if (tid == 7) {
      mw[i * 8 + 7] = row[768];
    }
  } else if (blk < 832) {
    int bv = blk - 768;
    __shared__ __align__(16) float cvs[264];
    cvs[tid] = prev[(size_t)bv * 256 + tid];
    if (tid < 8) cvs[256 + tid] = veh[bv * 8 + tid];
    __syncthreads();
    int b = bv >> 3;
    float a = fixedc[b * 256 + tid];
    const float4* c4 = (const float4*)cvs;
    const float4* w4 = (const float4*)(pcs + (size_t)tid * 264);
    #pragma unroll 8
    for (int k = 0; k < 66; k++) {
      float4 cv = c4[k], wv = w4[k];
      a += cv.x*wv.x + cv.y*wv.y + cv.z*wv.z + cv.w*wv.w;
    }
    queryp[(size_t)bv * 256 + tid] = a;
  } else {
    // parallel mask-dtype probe: int32 bool has bytes idx%4!=0 all zero;
    // u8 bool has ~70% of them nonzero. One byte per thread + ballot.
    __shared__ unsigned hits[4];
    const unsigned char* mb = (const unsigned char*)maskp;
    bool hit = (tid > 0) && ((tid & 3) != 0) && (mb[tid] != 0);
    unsigned long long bal = __ballot(hit);
    if ((tid & 63) == 0) hits[tid >> 6] = (bal != 0ull) ? 1u : 0u;
    __syncthreads();
    if (tid == 0) {
      ((unsigned*)(W + OFF_BM))[0] = hits[0] | hits[1] | hits[2] | hits[3];
      ((unsigned*)(W + OFF_DONE))[0] = 0u;
    }
  }
}

// ---------------- K_attn: 512 blocks = (h, c, b) ----------------
// compat -> exp (no max-sub; shift-invariant) -> partial slots (plain stores).
// r12: gKs slice staged (pad-36 rows); hstat register-blocked on wave 0
// (float4 acc, b128 gvL reads, v-broadcast conflict-free); s8 on tids 64..255
// overlapping hstat. LDS = 73.3 KB -> 2 blocks/CU.
__global__ __launch_bounds__(256) void k_attn(
    const float* __restrict__ node_dyn, const float* __restrict__ gVs,
    const float* __restrict__ gKs, const void* __restrict__ maskp,
    float* __restrict__ W)
{
  const int blk = blockIdx.x, tid = threadIdx.x;
  const int b = blk & 7, c = (blk >> 3) & 7, h = blk >> 6;
  const int n0 = c * 125;
  const float* mw     = W + OFF_MW;
  const float* queryp = W + OFF_QUERY;
  float* csum_p  = W + OFF_CSUMP;
  float* hstat_p = W + OFF_HSTATP;
  float* s8_p    = W + OFF_S8P;
  const int bytemode = *(const int*)(W + OFF_BM);   // uniform scalar load

  __shared__ __align__(16) float p[1000];
  __shared__ __align__(16) float gq[256];
  __shared__ float mwK[256];                 // [k=32][f=8], contiguous mw block
  __shared__ float qmk[64];
  __shared__ float red4[4];
  __shared__ float s8part[256];
  __shared__ __align__(16) float gvL[4000];  // [i=125][k=32] gVs slice
  __shared__ __align__(16) float gkL[4500];  // [i=125][36-pad] gKs slice
  __shared__ __align__(16) float ndL[8000];  // [e=1000][f=8] node_dyn slice

  gq[tid]  = queryp[(size_t)(b * 8 + (tid >> 5)) * 256 + h * 32 + (tid & 31)];
  mwK[tid] = mw[(256 + h * 32) * 8 + tid];   // coalesced 1 KB block
  __syncthreads();
  if (tid < 64) {
    int v = tid >> 3, f = tid & 7;
    float a = 0.f;
    #pragma unroll
    for (int k = 0; k < 32; k++)
      a += gq[v * 32 + k] * mwK[k * 8 + f];
    qmk[tid] = a;
  }
  // stage gVs + gKs slices while qmk computes: 2x 1000 float4, coalesced
  {
    const float4* gv4 = (const float4*)(gVs + ((size_t)(h * 8 + b) * 1000 + n0) * 32);
    const float4* gk4 = (const float4*)(gKs + ((size_t)(h * 8 + b) * 1000 + n0) * 32);
    for (int idx = tid; idx < 1000; idx += 256) {
      int row = idx >> 3, c4 = idx & 7;
      ((float4*)gvL)[idx] = gv4[idx];
      ((float4*)(gkL + row * 36))[c4] = gk4[idx];
    }
  }
  __syncthreads();

  float tsum = 0.f;
  for (int e = tid; e < 1000; e += 256) {
    int v = e / 125;
    int i = e - v * 125;
    int n = n0 + i;
    int bvn = (b * 8 + v) * 1000 + n;
    const float4* nd4 = (const float4*)(node_dyn + (size_t)bvn * 8);
    float4 ndA = nd4[0], ndB = nd4[1];
    ((float4*)ndL)[e * 2]     = ndA;          // capture for s8 phase
    ((float4*)ndL)[e * 2 + 1] = ndB;
    const float4* gk4 = (const float4*)(gkL + i * 36);
    const float4* gq4 = (const float4*)(gq + v * 32);
    float s = 0.f;
    #pragma unroll
    for (int k4 = 0; k4 < 8; k4++) {
      float4 g = gk4[k4], q = gq4[k4];
      s += g.x*q.x + g.y*q.y + g.z*q.z + g.w*q.w;
    }
    const float* qm = qmk + v * 8;
    float dyn = ndA.x*qm[0] + ndA.y*qm[1] + ndA.z*qm[2] + ndA.w*qm[3]
              + ndB.x*qm[4] + ndB.y*qm[5] + ndB.z*qm[6] + ndB.w*qm[7];
    bool on = bytemode ? (((const unsigned char*)maskp)[bvn] != 0)
                       : (((const int*)maskp)[bvn] != 0);
    float cc = (s + dyn) * 0.17677669529663687f + (on ? 0.f : -INFINITY);
    float pv = __expf(cc);
    p[e] = pv;
    tsum += pv;
  }
  tsum = waveSum(tsum);
  if ((tid & 63) == 0) red4[tid >> 6] = tsum;
  __syncthreads();
  if (tid == 0) csum_p[blk] = red4[0] + red4[1] + red4[2] + red4[3];

  if (tid < 64) {
    // hstat partial [v][k] — register-blocked: 4 outputs/thread (kq quad).
    // gvL b128: 8 distinct 4-bank groups, v-lanes broadcast -> conflict-free.
    // Each output's i-chain identical to r11 -> bit-exact.
    int v = tid >> 3, kq = tid & 7;
    const float* pr = p + v * 125;
    const float4* gv4 = ((const float4*)gvL) + kq;
    float4 a = make_float4(0.f, 0.f, 0.f, 0.f);
    #pragma unroll 5
    for (int i = 0; i < 125; i++) {
      float pi = pr[i];
      float4 g = gv4[i * 8];
      a.x += pi * g.x; a.y += pi * g.y; a.z += pi * g.z; a.w += pi * g.w;
    }
    ((float4*)(hstat_p + (size_t)blk * 256))[tid] = a;
  } else {
    // s8 partial [v][f], 4-way i-split — same slots/chains as r11, now on
    // threads 64..255 so it overlaps hstat. Threads 64..127 take 2 slots.
    int j0 = tid - 64;                       // 0..191
    #pragma unroll
    for (int rep = 0; rep < 2; rep++) {
      int t = j0 + rep * 192;
      if (t < 256) {
        int sidx = t & 3, vf = t >> 2;
        int v = vf >> 3, f = vf & 7;
        int i0 = sidx * 32;
        int iN = (sidx == 3) ? 29 : 32;      // 32+32+32+29 = 125
        const float* nd = ndL + ((size_t)(v * 125 + i0)) * 8 + f;
        const float* pr = p + v * 125 + i0;
        float a = 0.f;
        for (int i = 0; i < iN; i++) a += pr[i] * nd[i * 8];
        s8part[sidx * 64 + vf] = a;
      }
    }
  }
  __syncthreads();
  if (tid < 64)
    s8_p[(size_t)blk * 64 + tid] = s8part[tid] + s8part[64 + tid]
                                 + s8part[128 + tid] + s8part[192 + tid];
}

// ---------------- K_logits: 256 blocks = (b, slice of 32 nodes) -------------
// r13 fused: each block recomputes its b's fq[8][256] + lqm[8][8] from the
// k_attn partial slots with EXACTLY k_fq's accumulation chains (bit-exact),
// then does the per-(v,n) logit dot from LDS. Ticket last block -> outputs.
// r15: lqm (wave 0) overlapped with the main dot; barrier before lqmF use.
// r16: ticket-255 epilogue: parallel relaxed device-scope atomic loads.
__global__ __launch_bounds__(256) void k_logits(
    const float* __restrict__ lKs, const float* __restrict__ node_dyn,
    const void* __restrict__ maskp, const float* __restrict__ po,
    float* __restrict__ W, float* __restrict__ out)
{
  const int blk = blockIdx.x, tid = threadIdx.x;
  const int b = blk & 7, slice = blk >> 3;
  const int nn = tid >> 3, v = tid & 7;
  const int n = slice * 32 + nn;
  const bool valid = (n < 1000);
  const int n_c = valid ? n : 999;
  const float* mwgV    = W + OFF_MW;            // rows 0..255
  const float* mwgL    = W + OFF_MW + 512 * 8;  // rows 512..767
  const float* csum_p  = W + OFF_CSUMP;
  const float* hstat_p = W + OFF_HSTATP;
  const float* s8_p    = W + OFF_S8P;
  float* expsum_p = W + OFF_EXPSP;
  unsigned long long* packed_p = (unsigned long long*)(W + OFF_PACKP);
  unsigned* done = (unsigned*)(W + OFF_DONE);
  const int bytemode = *(const int*)(W + OFF_BM);   // uniform scalar load

  __shared__ __align__(16) float bkL[32 * 260];     // 32 lKs rows, +4f pad
  __shared__ __align__(16) float clL[8 * 256];      // conc rows (broadcast-read)
  __shared__ __align__(16) float fqlL[8 * 260];     // fq rows, +4f pad
  __shared__ float s8F[512];
  __shared__ float csumF[8];
  __shared__ float mwLL[2048];                      // mwgL staged coalesced
  __shared__ float lqmF[64];
  __shared__ float red4[4];
  __shared__ unsigned long long rP[4];
  __shared__ unsigned ticket;
  __shared__ float sS[256];                         // r16: parallel slot stage
  __shared__ unsigned long long sP[256];

  // (1) stage 32 lKs rows (clamped like n_c), coalesced: 2048 float4 total
  {
    const float4* src = (const float4*)(lKs + (size_t)b * 1000 * 256);
    for (int idx = tid; idx < 2048; idx += 256) {
      int row = idx >> 6, d4 = idx & 63;
      int ng = slice * 32 + row; if (ng > 999) ng = 999;
      ((float4*)(bkL + row * 260))[d4] = src[(size_t)ng * 64 + d4];
    }
  }
  // (2) slot reductions (chains match k_fq exactly: cc ascending)
  for (int idx = tid; idx < 512; idx += 256) {
    int h2 = idx >> 6, vf = idx & 63;
    float s = 0.f;
    #pragma unroll
    for (int cc = 0; cc < 8; cc++)
      s += s8_p[(size_t)((h2 << 6) | (cc << 3) | b) * 64 + vf];
    s8F[idx] = s;
  }
  if (tid < 8) {
    float s = 0.f;
    #pragma unroll
    for (int cc = 0; cc < 8; cc++) s += csum_p[(tid << 6) | (cc << 3) | b];
    csumF[tid] = s;
  }
  for (int idx = tid; idx < 2048; idx += 256) mwLL[idx] = mwgL[idx];
  // (3) hstat reduce, all 8 v rows in registers (tid = h2*32+k2, as k_fq)
  float hac[8];
  {
    const int k2 = tid & 31;
    #pragma unroll
    for (int v2 = 0; v2 < 8; v2++) hac[v2] = 0.f;
    #pragma unroll
    for (int cc = 0; cc < 8; cc++) {
      const float* hp = hstat_p + (size_t)((tid >> 5 << 6) | (cc << 3) | b) * 256;
      #pragma unroll
      for (int v2 = 0; v2 < 8; v2++) hac[v2] += hp[v2 * 32 + k2];
    }
  }
  __syncthreads();
  // (4) cl rows: same expression as k_fq's cl phase, per v
  {
    const int h2 = tid >> 5;
    float mwr[8];
    const float* mwp = mwgV + tid * 8;
    #pragma unroll
    for (int f = 0; f < 8; f++) mwr[f] = mwp[f];
    float inv = csumF[h2];
    #pragma unroll
    for (int v2 = 0; v2 < 8; v2++) {
      float dyn = 0.f;
      const float* s8pp = s8F + h2 * 64 + v2 * 8;
      #pragma unroll
      for (int f = 0; f < 8; f++) dyn += s8pp[f] * mwr[f];
      clL[v2 * 256 + tid] = (hac[v2] + dyn) / inv;
    }
  }
  __syncthreads();
  // (5) fq rows: thread tid computes fq[v][tid] = dot(cl[v], po[tid]) for all
  // v; d4 ascending, same per-iter expression as k_fq -> bit-exact. cl reads
  // are wave-broadcast; po row reads same pattern as k_fq.
  {
    float acc[8];
    #pragma unroll
    for (int v2 = 0; v2 < 8; v2++) acc[v2] = 0.f;
    const float4* w4 = (const float4*)(po + (size_t)tid * 256);
    #pragma unroll 4
    for (int e = 0; e < 64; e++) {
      float4 wv = w4[e];
      #pragma unroll
      for (int v2 = 0; v2 < 8; v2++) {
        float4 cv = ((const float4*)(clL + v2 * 256))[e];
        acc[v2] += cv.x*wv.x + cv.y*wv.y + cv.z*wv.z + cv.w*wv.w;
      }
    }
    #pragma unroll
    for (int v2 = 0; v2 < 8; v2++) fqlL[v2 * 260 + tid] = acc[v2];
  }
  __syncthreads();
  // (6) lqm on wave 0 (k_fq's exact two-level chain) OVERLAPPED with the
  // main-dot s on waves 1-3; barrier moved to before lqmF consumption.
  if (tid < 64) {
    int v2 = tid >> 3, f = tid & 7;
    const float* fr = fqlL + v2 * 260;
    float s2 = 0.f;
    for (int cc2 = 0; cc2 < 32; cc2++) {
      float p2 = 0.f;
      for (int d = cc2 * 8; d < cc2 * 8 + 8; d++) p2 += fr[d] * mwLL[d * 8 + f];
      s2 += p2;
    }
    lqmF[tid] = s2;
  }
  // (7) main logit dot — A from fqlL (260-pad rows: v*260 -> bank quads
  // 4v%32, conflict-free with 8-way broadcast), Bk from bkL as r11.
  int bvn = (b * 8 + v) * 1000 + n_c;
  const float4* A  = (const float4*)(fqlL + v * 260);
  const float4* Bk = (const float4*)(bkL + nn * 260);
  float s = 0.f;
  #pragma unroll 8
  for (int d4 = 0; d4 < 64; d4++) {
    float4 x = A[d4], y = Bk[d4];
    s += x.x*y.x + x.y*y.y + x.z*y.z + x.w*y.w;
  }
  const float4* nd4 = (const float4*)(node_dyn + (size_t)bvn * 8);
  float4 na = nd4[0], nb = nd4[1];
  __syncthreads();                          // lqmF ready
  const float* qm = lqmF + v * 8;
  float dyn = na.x*qm[0] + na.y*qm[1] + na.z*qm[2] + na.w*qm[3]
            + nb.x*qm[4] + nb.y*qm[5] + nb.z*qm[6] + nb.w*qm[7];
  float z = (s + dyn) * 0.0625f;
  bool on = bytemode ? (((const unsigned char*)maskp)[bvn] != 0)
                     : (((const int*)maskp)[bvn] != 0);
  float L = tanhf(z) * 10.0f + (on ? 0.f : -INFINITY);
  if (!valid) L = -INFINITY;
  float ex = __expf(L);                     // exp(-inf)=0
  unsigned idx = (unsigned)(v * 1000 + n_c);
  unsigned long long pk = ((unsigned long long)encF(L) << 32) | (unsigned)(~idx);
  float sEx = waveSum(ex);
  unsigned long long mP = waveMaxU(pk);
  if ((tid & 63) == 0) { red4[tid >> 6] = sEx; rP[tid >> 6] = mP; }
  __syncthreads();
  if (tid == 0) {
    float S = red4[0] + red4[1] + red4[2] + red4[3];
    unsigned long long P = rP[0];
    #pragma unroll
    for (int i = 1; i < 4; i++) P = (rP[i] > P) ? rP[i] : P;
    atomicExch(&expsum_p[blk], S);          // coherent-point slot stores
    atomicExch(&packed_p[blk], P);
    __threadfence();
    ticket = atomicAdd(done, 1u);
  }
  __syncthreads();
  if (ticket == 255) {                      // last block: all slots written
    __threadfence();
    // r16: 256 PARALLEL device-scope relaxed atomic loads into LDS.
    sS[tid] = __hip_atomic_load(&expsum_p[tid], __ATOMIC_RELAXED,
                                __HIP_MEMORY_SCOPE_AGENT);
    sP[tid] = __hip_atomic_load(&packed_p[tid], __ATOMIC_RELAXED,
                                __HIP_MEMORY_SCOPE_AGENT);
    __syncthreads();
    if (tid < 64) {
      float cEnt = 0.f;
      if (tid < 8) {
        float S = 0.f;
        unsigned long long P = 0ull;
        for (int sl = 0; sl < 32; sl++) {
          int j = sl * 8 + tid;             // slots of batch tid — same chain
          S += sS[j];
          unsigned long long q = sP[j];
          P = (q > P) ? q : P;
        }
        float best = decF((unsigned)(P >> 32));
        unsigned bi = ~(unsigned)(P & 0xffffffffu);
        float logprob = best - logf(S);
        float prob = __expf(logprob);
        out[tid]      = (float)(bi / 1000);
        out[8 + tid]  = (float)(bi % 1000);
        out[16 + tid] = logprob;
        cEnt = prob * logprob;
      }
      cEnt = waveSum(cEnt);
      if (tid == 0) out[24] = -cEnt;
    }
  }
}

extern "C" void kernel_launch(void* const* d_in, const int* in_sizes, int n_in,
                              void* d_out, int out_size, void* d_ws, size_t ws_size,
                              hipStream_t stream) {
  const float* fixedc   = (const float*)d_in[1];
  const float* prev     = (const float*)d_in[2];
  const float* node_dyn = (const float*)d_in[3];
  const float* veh      = (const float*)d_in[4];
  const float* gVs      = (const float*)d_in[5];
  const float* gKs      = (const float*)d_in[6];
  const float* lKs      = (const float*)d_in[7];
  const void*  mask     = d_in[8];
  const float* pcs      = (const float*)d_in[9];
  const float* pns1     = (const float*)d_in[10];
  const float* pns2     = (const float*)d_in[11];
  const float* po       = (const float*)d_in[12];
  float* W   = (float*)d_ws;
  float* out = (float*)d_out;

  k_prep<<<833, 256, 0, stream>>>(pns1, pns2, prev, veh, fixedc, pcs, mask, W);
  k_attn<<<512, 256, 0, stream>>>(node_dyn, gVs, gKs, mask, W);
  k_logits<<<256, 256, 0, stream>>>(lKs, node_dyn, mask, po, W, out);
}